// Round 11
// baseline (288.457 us; speedup 1.0000x reference)
//
#include <hip/hip_runtime.h>

// Fused MHA: X[4,2048,1024] fp32; W_K,W_Q,W_V,W_out[1024,1024]; b_out[1024].
//   1. prep:      convert X->bf16 (blocks<8192) + transpose W->Wt bf16 (rest)
//   2. gemm_qkv8: fused QKV, 256x128 tile, 8 waves, BK=64, 3-buffer LDS ring,
//                 counted vmcnt(6) (T4), 4 phases/K-tile + setprio (T3/T5),
//                 XOR-swizzled LDS both-sides (T2, rule 21), XCD swizzle (T1).
//                 Q (scaled 0.125*log2e) [s][1024]; K head-major Kh[bh][s][64];
//                 V tiled Vb[bh][t][d][s64]
//   3. attn:      swapped-operand flash attn; K/V tiles staged to LDS, dbuf
//   4. gemm_out:  2-phase dbuf + swizzle + swapped-operand -> float4 stores
typedef float  f32x4  __attribute__((ext_vector_type(4)));
typedef float  f32x16 __attribute__((ext_vector_type(16)));
typedef __bf16 bf16x8 __attribute__((ext_vector_type(8)));
typedef unsigned int u32x4 __attribute__((ext_vector_type(4)));

#define DIM   1024
#define SEQ   2048
#define HDIM  64

static __device__ __forceinline__ unsigned short f2bf(float f) {
  unsigned int u = __builtin_bit_cast(unsigned int, f);
  u += 0x7fffu + ((u >> 16) & 1u);   // RNE
  return (unsigned short)(u >> 16);
}

static __device__ __forceinline__ float exp2a(float x) {
#if __has_builtin(__builtin_amdgcn_exp2f)
  return __builtin_amdgcn_exp2f(x);
#else
  return exp2f(x);
#endif
}

static __device__ __forceinline__ void pswap(unsigned& a, unsigned& b) {
#if __has_builtin(__builtin_amdgcn_permlane32_swap)
  auto r = __builtin_amdgcn_permlane32_swap(a, b, false, false);
  a = r[0]; b = r[1];
#else
  asm volatile("v_permlane32_swap_b32 %0, %1" : "+v"(a), "+v"(b));
#endif
}

#define CVTPK(lo_, hi_) ({ unsigned r_;                                                 \
  asm("v_cvt_pk_bf16_f32 %0, %1, %2" : "=v"(r_) : "v"(lo_), "v"(hi_)); r_; })

// async global->LDS, 16B per lane; lds dest = wave-uniform base + lane*16
#define GLDS16(g, l)                                                                    \
  __builtin_amdgcn_global_load_lds((__attribute__((address_space(1))) void*)(g),        \
                                   (__attribute__((address_space(3))) void*)(l), 16, 0, 0)

// ---- prep: fused convert_x + transpose_w ----
__global__ __launch_bounds__(256) void prep(const float* __restrict__ X,
                                            ushort4* __restrict__ Xb,
                                            const float* __restrict__ WQ,
                                            const float* __restrict__ WK,
                                            const float* __restrict__ WV,
                                            const float* __restrict__ WO,
                                            unsigned short* __restrict__ WtAll) {
  const int bid = blockIdx.x;
  __shared__ float tile[32][33];
  if (bid < 8192) {
    int i = bid * 256 + threadIdx.x;
    float4 v = ((const float4*)X)[i];
    ushort4 o;
    o.x = f2bf(v.x); o.y = f2bf(v.y); o.z = f2bf(v.z); o.w = f2bf(v.w);
    Xb[i] = o;
  } else {
    const int b2 = bid - 8192;
    const int z = b2 >> 10;
    const int xy = b2 & 1023;
    const int bx = xy & 31, by = xy >> 5;
    const float* W = (z == 0) ? WQ : (z == 1) ? WK : (z == 2) ? WV : WO;
    unsigned short* Wt = WtAll + (size_t)z * (DIM * DIM);
    const int tx = threadIdx.x & 31, ty = threadIdx.x >> 5;   // 32 x 8
    const int n0 = bx * 32, k0 = by * 32;
#pragma unroll
    for (int r = 0; r < 4; ++r)
      tile[ty + 8 * r][tx] = W[(size_t)(k0 + ty + 8 * r) * DIM + n0 + tx];
    __syncthreads();
#pragma unroll
    for (int r = 0; r < 4; ++r)
      Wt[(size_t)(n0 + ty + 8 * r) * DIM + k0 + tx] = f2bf(tile[tx][ty + 8 * r]);
  }
}

// ---- fused QKV GEMM: 256x128 tile, 8 waves, 3-buffer counted-vmcnt ring ----
// LDS rows = 128B, XOR swizzle byte ^= ((row&7)<<4) on global source AND reads.
// Per K-tile: A = 4 issues (8KB each), B = 2 issues; stage t+2 during t;
// end-of-tile s_waitcnt vmcnt(6) drains t+1's 6 issues (issued 1 tile ago).
template<bool SW>
static __device__ __forceinline__ void kloop8(const unsigned short* __restrict__ Xb,
                                              const unsigned short* __restrict__ Wt3,
                                              unsigned short* As, unsigned short* Bs,
                                              int m0, int n0g, f32x4 acc[4][4]) {
  const int tid = threadIdx.x;
  const int lane = tid & 63, wave = tid >> 6;
  const int l15 = lane & 15, lg = lane >> 4;
  const int wm = (wave >> 1) * 64, wn = (wave & 1) * 64;
  const int rswz = (l15 & 7) << 4;

  const int rA = tid >> 3;                               // row within issue (0..63)
  const int cx = ((tid & 7) * 16) ^ ((rA & 7) << 4);     // pre-swizzled col bytes
  const char* gA = (const char*)Xb + ((size_t)(m0 + rA) * DIM) * 2 + cx;
  const char* gB = (const char*)Wt3 + ((size_t)(n0g + rA) * DIM) * 2 + cx;

  auto STAGE_A = [&](int buf, int kt, int j) {
    GLDS16(gA + (size_t)j * (64 * 2048) + kt * 2, &As[buf * 16384 + j * 4096 + wave * 512]);
  };
  auto STAGE_B = [&](int buf, int kt, int j) {
    GLDS16(gB + (size_t)j * (64 * 2048) + kt * 2, &Bs[buf * 8192 + j * 4096 + wave * 512]);
  };
  auto LDA = [&](int buf, int fr, int kk) {
    return *(const bf16x8*)&As[buf * 16384 + (wm + fr * 16 + l15) * 64 +
                               (((kk * 64 + lg * 16) ^ rswz) >> 1)];
  };
  auto LDB = [&](int buf, int ni, int kk) {
    return *(const bf16x8*)&Bs[buf * 8192 + (wn + ni * 16 + l15) * 64 +
                               (((kk * 64 + lg * 16) ^ rswz) >> 1)];
  };

  // prologue: tile 0 -> buf0, tile 1 -> buf1
#pragma unroll
  for (int j = 0; j < 4; ++j) STAGE_A(0, 0, j);
#pragma unroll
  for (int j = 0; j < 2; ++j) STAGE_B(0, 0, j);
#pragma unroll
  for (int j = 0; j < 4; ++j) STAGE_A(1, 64, j);
#pragma unroll
  for (int j = 0; j < 2; ++j) STAGE_B(1, 64, j);
  asm volatile("s_waitcnt vmcnt(6)" ::: "memory");   // tile0 landed; tile1 in flight
  __builtin_amdgcn_s_barrier();

  for (int t = 0; t < 16; ++t) {
    const int buf = t % 3;
    const int b2 = (t + 2) % 3;
    const int kt2 = (t + 2) * 64;
    const bool pre = (t + 2) < 16;
    bf16x8 bq[4][2];
#pragma unroll
    for (int p = 0; p < 4; ++p) {
      if (pre) {
        if (p == 0) { STAGE_A(b2, kt2, 0); STAGE_A(b2, kt2, 1); STAGE_A(b2, kt2, 2); }
        else if (p == 1) { STAGE_A(b2, kt2, 3); STAGE_B(b2, kt2, 0); STAGE_B(b2, kt2, 1); }
      }
      if (p == 0) {
#pragma unroll
        for (int ni = 0; ni < 4; ++ni) {
          bq[ni][0] = LDB(buf, ni, 0);
          bq[ni][1] = LDB(buf, ni, 1);
        }
      }
      bf16x8 a0 = LDA(buf, p, 0);
      bf16x8 a1 = LDA(buf, p, 1);
      asm volatile("s_waitcnt lgkmcnt(0)" ::: "memory");
      __builtin_amdgcn_sched_barrier(0);               // rule 18: pin MFMA after wait
      __builtin_amdgcn_s_setprio(1);
#pragma unroll
      for (int ni = 0; ni < 4; ++ni) {
        if (SW) {
          acc[p][ni] = __builtin_amdgcn_mfma_f32_16x16x32_bf16(bq[ni][0], a0, acc[p][ni], 0, 0, 0);
          acc[p][ni] = __builtin_amdgcn_mfma_f32_16x16x32_bf16(bq[ni][1], a1, acc[p][ni], 0, 0, 0);
        } else {
          acc[p][ni] = __builtin_amdgcn_mfma_f32_16x16x32_bf16(a0, bq[ni][0], acc[p][ni], 0, 0, 0);
          acc[p][ni] = __builtin_amdgcn_mfma_f32_16x16x32_bf16(a1, bq[ni][1], acc[p][ni], 0, 0, 0);
        }
      }
      __builtin_amdgcn_s_setprio(0);
      if (p < 3) __builtin_amdgcn_s_barrier();
    }
    if (t < 14)       asm volatile("s_waitcnt vmcnt(6)" ::: "memory");
    else if (t == 14) asm volatile("s_waitcnt vmcnt(0)" ::: "memory");
    __builtin_amdgcn_s_barrier();
  }
}

__global__ __launch_bounds__(512) void gemm_qkv8(const unsigned short* __restrict__ Xb,
                                                 const unsigned short* __restrict__ WtAll,
                                                 unsigned short* __restrict__ Qb,
                                                 unsigned short* __restrict__ Kh,
                                                 unsigned short* __restrict__ Vb) {
  __shared__ __align__(16) unsigned short As[3 * 16384];   // 96 KB
  __shared__ __align__(16) unsigned short Bs[3 * 8192];    // 48 KB
  const int wg = blockIdx.x;
  const int sw = (wg & 7) * 96 + (wg >> 3);                // XCD swizzle (768%8==0)
  const int ntile = sw >> 5, mtile = sw & 31;
  const int m0 = mtile * 256, n0g = ntile * 128;
  const int z = n0g >> 10, n0z = n0g & 1023;

  f32x4 acc[4][4] = {};
  if (z < 2) kloop8<true>(Xb, WtAll, As, Bs, m0, n0g, acc);
  else       kloop8<false>(Xb, WtAll, As, Bs, m0, n0g, acc);

  const int lane = threadIdx.x & 63, wave = threadIdx.x >> 6;
  const int l15 = lane & 15, lg = lane >> 4;
  const int wm = (wave >> 1) * 64, wn = (wave & 1) * 64;

  if (z == 0) {
    const float scale = (float)(0.125 * 1.4426950408889634);
#pragma unroll
    for (int mi = 0; mi < 4; ++mi)
#pragma unroll
      for (int ni = 0; ni < 4; ++ni) {
        const int s = m0 + wm + mi * 16 + l15;
        const int nq = n0z + wn + ni * 16 + lg * 4;
        ushort4 v;
        v.x = f2bf(acc[mi][ni][0] * scale); v.y = f2bf(acc[mi][ni][1] * scale);
        v.z = f2bf(acc[mi][ni][2] * scale); v.w = f2bf(acc[mi][ni][3] * scale);
        *(ushort4*)&Qb[(size_t)s * DIM + nq] = v;
      }
  } else if (z == 1) {
#pragma unroll
    for (int mi = 0; mi < 4; ++mi)
#pragma unroll
      for (int ni = 0; ni < 4; ++ni) {
        const int s = m0 + wm + mi * 16 + l15;
        const int b = s >> 11, sl = s & 2047;
        const int nq = n0z + wn + ni * 16 + lg * 4;
        const int h = nq >> 6, d = nq & 63;
        ushort4 v;
        v.x = f2bf(acc[mi][ni][0]); v.y = f2bf(acc[mi][ni][1]);
        v.z = f2bf(acc[mi][ni][2]); v.w = f2bf(acc[mi][ni][3]);
        *(ushort4*)&Kh[((size_t)(b * 16 + h) * 2048 + sl) * 64 + d] = v;
      }
  } else {
#pragma unroll
    for (int mi = 0; mi < 4; ++mi)
#pragma unroll
      for (int ni = 0; ni < 4; ++ni) {
        const int n = n0z + wn + ni * 16 + l15;
        const int h = n >> 6, d = n & 63;
        const int s4 = m0 + wm + mi * 16 + lg * 4;
        const int b = s4 >> 11, sq = s4 & 2047;
        const int tt = sq >> 6, si = sq & 63;
        ushort4 v;
        v.x = f2bf(acc[mi][ni][0]); v.y = f2bf(acc[mi][ni][1]);
        v.z = f2bf(acc[mi][ni][2]); v.w = f2bf(acc[mi][ni][3]);
        *(ushort4*)&Vb[((((size_t)(b * 16 + h) * 32 + tt) * 64 + d) * 64) + si] = v;
      }
  }
}

// ---- swapped-operand causal flash attention with LDS-staged K/V tiles ----
__global__ __launch_bounds__(256) void attn(const unsigned short* __restrict__ Qb,
                                            const unsigned short* __restrict__ Kh,
                                            const unsigned short* __restrict__ Vb,
                                            unsigned short* __restrict__ Cb) {
  const int bh = blockIdx.x;
  const int qt = (gridDim.y - 1) - blockIdx.y;        // heavy q-tiles first
  const int b = bh >> 4;
  const int tid = threadIdx.x;
  const int lane = tid & 63, wave = tid >> 6;
  const int l31 = lane & 31, hi = lane >> 5;
  const int swz = (l31 & 7) << 4;
  const int q_base = qt * 128 + wave * 32;
  const int q = q_base + l31;

  __shared__ __align__(16) char LDS[2][16384];

  int soff0, soff1;
  {
    const int L0 = wave * 2048 + lane * 16;
    const int r0 = L0 >> 7;
    soff0 = r0 * 128 + ((L0 & 127) ^ ((r0 & 7) << 4));
    const int L1 = L0 + 1024;
    const int r1 = L1 >> 7;
    soff1 = r1 * 128 + ((L1 & 127) ^ ((r1 & 7) << 4));
  }
  const char* Kt0 = (const char*)Kh + ((size_t)bh * 2048) * 128;
  const char* Vt0 = (const char*)Vb + ((size_t)bh * 32) * 8192;

  const unsigned short* Qp = Qb + (size_t)(b * SEQ + q) * DIM + (bh & 15) * HDIM + hi * 8;
  bf16x8 qf[4];
#pragma unroll
  for (int ks = 0; ks < 4; ++ks) qf[ks] = *(const bf16x8*)(Qp + ks * 16);

  float m_r = -INFINITY, l_r = 0.f;
  f32x16 o0 = {}, o1 = {};

  const int n_tiles = 2 * qt + 2;
  int cur = 0;

  {
    char* lK = &LDS[0][wave * 2048];
    char* lV = &LDS[0][8192 + wave * 2048];
    GLDS16(Kt0 + soff0, lK); GLDS16(Kt0 + soff1, lK + 1024);
    GLDS16(Vt0 + soff0, lV); GLDS16(Vt0 + soff1, lV + 1024);
  }
  __syncthreads();

  for (int t = 0; t < n_tiles; ++t) {
    const int kv0 = t << 6;
    if (t + 1 < n_tiles) {
      const char* kb = Kt0 + (size_t)(t + 1) * 8192;
      const char* vb = Vt0 + (size_t)(t + 1) * 8192;
      char* lK = &LDS[cur ^ 1][wave * 2048];
      char* lV = &LDS[cur ^ 1][8192 + wave * 2048];
      GLDS16(kb + soff0, lK); GLDS16(kb + soff1, lK + 1024);
      GLDS16(vb + soff0, lV); GLDS16(vb + soff1, lV + 1024);
    }

    if (kv0 <= q_base + 31) {
      const char* Lb = &LDS[cur][0];
      f32x16 st0 = {}, st1 = {};
      __builtin_amdgcn_s_setprio(1);
#pragma unroll
      for (int ks = 0; ks < 4; ++ks) {
        const char* a = Lb + l31 * 128 + ((ks * 32 + hi * 16) ^ swz);
        bf16x8 kf0 = *(const bf16x8*)(a);
        bf16x8 kf1 = *(const bf16x8*)(a + 4096);
        st0 = __builtin_amdgcn_mfma_f32_32x32x16_bf16(kf0, qf[ks], st0, 0, 0, 0);
        st1 = __builtin_amdgcn_mfma_f32_32x32x16_bf16(kf1, qf[ks], st1, 0, 0, 0);
      }
      __builtin_amdgcn_s_setprio(0);

      if (kv0 + 63 > q_base) {
        const int qm = q - kv0 - 4 * hi;
#pragma unroll
        for (int r = 0; r < 16; ++r) {
          const int c = (r & 3) + 8 * (r >> 2);
          if (c > qm)      st0[r] = -INFINITY;
          if (c + 32 > qm) st1[r] = -INFINITY;
        }
      }

      float tmax = st0[0];
#pragma unroll
      for (int r = 1; r < 16; ++r) tmax = fmaxf(tmax, st0[r]);
#pragma unroll
      for (int r = 0; r < 16; ++r) tmax = fmaxf(tmax, st1[r]);
      tmax = fmaxf(tmax, __shfl_xor(tmax, 32));

      if (__any(!(tmax <= m_r + 8.0f))) {
        const float mn = fmaxf(m_r, tmax);
        const float al = exp2a(m_r - mn);
        m_r = mn;
        l_r *= al;
        o0 *= al;
        o1 *= al;
      }

#pragma unroll
      for (int r = 0; r < 16; ++r) st0[r] = exp2a(st0[r] - m_r);
#pragma unroll
      for (int r = 0; r < 16; ++r) st1[r] = exp2a(st1[r] - m_r);
      float ps = 0.f;
#pragma unroll
      for (int r = 0; r < 16; ++r) ps += st0[r] + st1[r];
      ps += __shfl_xor(ps, 32);
      l_r += ps;

      u32x4 pf[4];
      {
        unsigned a, bb;
        a = CVTPK(st0[0], st0[1]);   bb = CVTPK(st0[4], st0[5]);   pswap(a, bb); pf[0][0] = a; pf[0][2] = bb;
        a = CVTPK(st0[2], st0[3]);   bb = CVTPK(st0[6], st0[7]);   pswap(a, bb); pf[0][1] = a; pf[0][3] = bb;
        a = CVTPK(st0[8], st0[9]);   bb = CVTPK(st0[12], st0[13]); pswap(a, bb); pf[1][0] = a; pf[1][2] = bb;
        a = CVTPK(st0[10], st0[11]); bb = CVTPK(st0[14], st0[15]); pswap(a, bb); pf[1][1] = a; pf[1][3] = bb;
        a = CVTPK(st1[0], st1[1]);   bb = CVTPK(st1[4], st1[5]);   pswap(a, bb); pf[2][0] = a; pf[2][2] = bb;
        a = CVTPK(st1[2], st1[3]);   bb = CVTPK(st1[6], st1[7]);   pswap(a, bb); pf[2][1] = a; pf[2][3] = bb;
        a = CVTPK(st1[8], st1[9]);   bb = CVTPK(st1[12], st1[13]); pswap(a, bb); pf[3][0] = a; pf[3][2] = bb;
        a = CVTPK(st1[10], st1[11]); bb = CVTPK(st1[14], st1[15]); pswap(a, bb); pf[3][1] = a; pf[3][3] = bb;
      }

      __builtin_amdgcn_s_setprio(1);
#pragma unroll
      for (int ks = 0; ks < 4; ++ks) {
        const char* a = Lb + 8192 + l31 * 128 + ((ks * 32 + hi * 16) ^ swz);
        bf16x8 v0 = *(const bf16x8*)(a);
        bf16x8 v1 = *(const bf16x8*)(a + 4096);
        bf16x8 pb = __builtin_bit_cast(bf16x8, pf[ks]);
        o0 = __builtin_amdgcn_mfma_f32_32x32x16_bf16(v0, pb, o0, 0, 0, 0);
        o1 = __builtin_amdgcn_mfma_f32_32x32x16_bf16(v1, pb, o1, 0, 0, 0);
      }
      __builtin_amdgcn_s_setprio(0);
    }

    __syncthreads();
    cur ^= 1;
  }

  const float rl = 1.0f / l_r;
  unsigned short* Co = Cb + (size_t)(b * SEQ + q) * DIM + (bh & 15) * HDIM;
#pragma unroll
  for (int j = 0; j < 4; ++j) {
    ushort4 w0, w1;
    w0.x = f2bf(o0[4 * j + 0] * rl); w0.y = f2bf(o0[4 * j + 1] * rl);
    w0.z = f2bf(o0[4 * j + 2] * rl); w0.w = f2bf(o0[4 * j + 3] * rl);
    w1.x = f2bf(o1[4 * j + 0] * rl); w1.y = f2bf(o1[4 * j + 1] * rl);
    w1.z = f2bf(o1[4 * j + 2] * rl); w1.w = f2bf(o1[4 * j + 3] * rl);
    *(ushort4*)(Co + 8 * j + 4 * hi) = w0;
    *(ushort4*)(Co + 32 + 8 * j + 4 * hi) = w1;
  }
}

// ---- output projection: 2-phase dbuf + swizzle + swapped operands ----
__global__ __launch_bounds__(256) void gemm_out(const unsigned short* __restrict__ Cb,
                                                const unsigned short* __restrict__ WtO,
                                                const float* __restrict__ bias,
                                                float* __restrict__ out) {
  const int m0 = blockIdx.x * 128, n0 = blockIdx.y * 128;
  const int lane = threadIdx.x & 63, wave = threadIdx.x >> 6;
  const int wr = wave >> 1, wc = wave & 1;
  const int l15 = lane & 15, lg = lane >> 4;
  const int rowA = lane >> 2;
  const int colS = (((lane & 3) ^ ((rowA >> 1) & 3)) * 8);
  const int slotS = ((lg ^ ((l15 >> 1) & 3)) * 8);
  const int sA = wave * 2;
  __shared__ __align__(16) unsigned short As[2][128 * 32], Bs[2][128 * 32];
  f32x4 acc[4][4] = {};

  auto STAGE = [&](int buf, int kt) {
    GLDS16(Cb  + (size_t)(m0 + (sA + 0) * 16 + rowA) * DIM + kt + colS, &As[buf][(sA + 0) * 512]);
    GLDS16(Cb  + (size_t)(m0 + (sA + 1) * 16 + rowA) * DIM + kt + colS, &As[buf][(sA + 1) * 512]);
    GLDS16(WtO + (size_t)(n0 + (sA + 0) * 16 + rowA) * DIM + kt + colS, &Bs[buf][(sA + 0) * 512]);
    GLDS16(WtO + (size_t)(n0 + (sA + 1) * 16 + rowA) * DIM + kt + colS, &Bs[buf][(sA + 1) * 512]);
  };

  STAGE(0, 0);
  __syncthreads();
  int cur = 0;
  for (int kt = 0; kt < DIM; kt += 32) {
    if (kt + 32 < DIM) STAGE(cur ^ 1, kt + 32);
    bf16x8 af[4], bfr[4];
#pragma unroll
    for (int mi = 0; mi < 4; ++mi)
      af[mi] = *(const bf16x8*)&As[cur][(wr * 64 + mi * 16 + l15) * 32 + slotS];
#pragma unroll
    for (int ni = 0; ni < 4; ++ni)
      bfr[ni] = *(const bf16x8*)&Bs[cur][(wc * 64 + ni * 16 + l15) * 32 + slotS];
#pragma unroll
    for (int mi = 0; mi < 4; ++mi)
#pragma unroll
      for (int ni = 0; ni < 4; ++ni)
        acc[mi][ni] = __builtin_amdgcn_mfma_f32_16x16x32_bf16(bfr[ni], af[mi], acc[mi][ni], 0, 0, 0);
    __syncthreads();
    cur ^= 1;
  }

#pragma unroll
  for (int mi = 0; mi < 4; ++mi)
#pragma unroll
    for (int ni = 0; ni < 4; ++ni) {
      const int s = m0 + wr * 64 + mi * 16 + l15;
      const int nb = n0 + wc * 64 + ni * 16 + lg * 4;
      const float4 bv = *(const float4*)&bias[nb];
      float4 o;
      o.x = acc[mi][ni][0] + bv.x; o.y = acc[mi][ni][1] + bv.y;
      o.z = acc[mi][ni][2] + bv.z; o.w = acc[mi][ni][3] + bv.w;
      *(float4*)&out[(size_t)s * DIM + nb] = o;
    }
}

extern "C" void kernel_launch(void* const* d_in, const int* in_sizes, int n_in,
                              void* d_out, int out_size, void* d_ws, size_t ws_size,
                              hipStream_t stream) {
  const float* X  = (const float*)d_in[0];
  const float* WK = (const float*)d_in[1];
  const float* WQ = (const float*)d_in[2];
  const float* WV = (const float*)d_in[3];
  const float* WO = (const float*)d_in[4];
  const float* bo = (const float*)d_in[5];
  float* out = (float*)d_out;

  char* ws = (char*)d_ws;
  unsigned short* Xb    = (unsigned short*)(ws);                  // 16 MB (reused as Cb)
  unsigned short* WtAll = (unsigned short*)(ws + (16u << 20));    // 8 MB
  unsigned short* Qb    = (unsigned short*)(ws + (24u << 20));    // 16 MB
  unsigned short* Kh    = (unsigned short*)(ws + (40u << 20));    // 16 MB head-major K
  unsigned short* Vb    = (unsigned short*)(ws + (56u << 20));    // 16 MB tiled V
  unsigned short* Cb    = Xb;

  prep<<<12288, 256, 0, stream>>>(X, (ushort4*)Xb, WQ, WK, WV, WO, WtAll);
  gemm_qkv8<<<768, 512, 0, stream>>>(Xb, WtAll, Qb, Kh, Vb);
  attn<<<dim3(64, 16), 256, 0, stream>>>(Qb, Kh, Vb, Cb);
  gemm_out<<<dim3(64, 8), 256, 0, stream>>>(Cb, WtAll + 3u * 1048576u, bo, out);
}